// Round 9
// baseline (423.098 us; speedup 1.0000x reference)
//
#include <hip/hip_runtime.h>
#include <hip/hip_bf16.h>
#include <math.h>

#define D_MODEL 1024
#define D_STATE 16
#define D_CONV  4
#define BATCH   2
#define SEQ     2048
#define MROWS   (BATCH * SEQ)   // 4096
#define CHUNK   32
#define NCHUNK  (SEQ / CHUNK)   // 64
#define BD      (BATCH * D_MODEL)   // 2048

typedef __attribute__((ext_vector_type(8))) short bf16x8;
typedef __attribute__((ext_vector_type(4))) float f32x4;

#define LSTRIDE 68   // LDS row stride in elems (136 B): staggers ds_read banks

__device__ __forceinline__ unsigned short f2bf(float f) {
    unsigned int u = __builtin_bit_cast(unsigned int, f);
    u = (u + 0x7fffu + ((u >> 16) & 1u)) >> 16;
    return (unsigned short)u;
}
__device__ __forceinline__ float bf2f(unsigned short u) {
    return __builtin_bit_cast(float, (unsigned int)u << 16);
}
__device__ __forceinline__ float softplus_f(float v) {
    return (v > 20.f) ? v : log1pf(expf(v));
}

// barrier that does NOT drain vmcnt: publish LDS writes (lgkmcnt(0)) + s_barrier.
// 0xc07f = vmcnt(63) expcnt(7) lgkmcnt(0)  -> waits LDS/SMEM only.
__device__ __forceinline__ void lds_barrier() {
    __builtin_amdgcn_s_waitcnt(0xc07f);
    __builtin_amdgcn_s_barrier();
}

// ---------------------------------------------------------------------------
// Merged prepass (unchanged from R8)
// ---------------------------------------------------------------------------
__global__ __launch_bounds__(256) void prepass(
        const float* __restrict__ x, unsigned short* __restrict__ xb,
        const float* __restrict__ W_in, unsigned short* __restrict__ Wt_in,
        const float* __restrict__ W_dt, unsigned short* __restrict__ Wt_cat,
        const float* __restrict__ W_out, unsigned short* __restrict__ Wt_out,
        const float* __restrict__ Wx) {
    __shared__ float tile[32][33];
    const int blk = blockIdx.x;
    const int tid = threadIdx.x;

    if (blk < 2048) {                       // region 0: cvt x
        const size_t i = ((size_t)blk * 256 + tid) * 8;
        const float4 v0 = *(const float4*)(x + i);
        const float4 v1 = *(const float4*)(x + i + 4);
        bf16x8 o;
        o[0] = (short)f2bf(v0.x); o[1] = (short)f2bf(v0.y);
        o[2] = (short)f2bf(v0.z); o[3] = (short)f2bf(v0.w);
        o[4] = (short)f2bf(v1.x); o[5] = (short)f2bf(v1.y);
        o[6] = (short)f2bf(v1.z); o[7] = (short)f2bf(v1.w);
        *(bf16x8*)(xb + i) = o;
        return;
    }
    if (blk < 2048 + 2048 + 1024 + 1024) {  // regions 1-3: transpose
        const float* W; unsigned short* Wt; int N, b;
        if (blk < 4096)      { W = W_in;  Wt = Wt_in;  N = 2048; b = blk - 2048; }
        else if (blk < 5120) { W = W_dt;  Wt = Wt_cat; N = 1024; b = blk - 4096; }
        else                 { W = W_out; Wt = Wt_out; N = 1024; b = blk - 5120; }
        const int nx = N / 32;
        const int n0 = (b % nx) * 32, k0 = (b / nx) * 32;
        const int tx = tid & 31, ty = tid >> 5;
#pragma unroll
        for (int r = 0; r < 4; ++r)
            tile[ty + r * 8][tx] = W[(size_t)(k0 + ty + r * 8) * N + n0 + tx];
        __syncthreads();
#pragma unroll
        for (int r = 0; r < 4; ++r)
            Wt[(size_t)(n0 + ty + r * 8) * 1024 + k0 + tx] = f2bf(tile[tx][ty + r * 8]);
        return;
    }
    {                                        // region 4: wx_stage
        const int idx = (blk - 6144) * 256 + tid;   // 0 .. 128*1024-1
        const int k = idx & 1023;
        const int n = idx >> 10;
        unsigned short v = 0;
        if (n < 32) v = f2bf(Wx[(size_t)k * 32 + n]);
        Wt_cat[(size_t)(1024 + n) * 1024 + k] = v;
    }
}

// ---------------------------------------------------------------------------
// MFMA GEMM: C[M x N] = epi(A[M x K] @ Bt[N x K]^T), bf16 in, fp32 acc.
// 64(M) x 128(N) tile, BK=64, 4 waves. REGISTER-STAGED PIPELINE, depth 2:
//   iter i: issue global loads tile i+2 -> regs; compute tile i from LDS;
//           ds_write regs(tile i+1) -> LDS (compiler emits fine vmcnt(N));
//           lgkmcnt(0)-only barrier (NO vmcnt drain -> loads stay in flight
//           across the barrier, hipBLASLt-style).
// LDS rows padded to 68 elems. EPI: 0 fp32, 2 bf16, 3 fused dt/BC.
// ---------------------------------------------------------------------------
template <int EPI>
__global__ __launch_bounds__(256) void gemm64(
        const unsigned short* __restrict__ A, const unsigned short* __restrict__ Bt,
        void* __restrict__ Cout, int N, int K,
        const float* __restrict__ bias, const float* __restrict__ alog,
        float* __restrict__ bc) {
    __shared__ unsigned short As[2][64 * LSTRIDE];    // 17.4 KB total
    __shared__ unsigned short Bs[2][128 * LSTRIDE];   // 34.8 KB total

    const int tid  = threadIdx.x;
    const int wave = tid >> 6, lane = tid & 63;
    const int q = lane >> 4, mr = lane & 15;
    const int m0 = blockIdx.y * 64, n0 = blockIdx.x * 128;

    f32x4 acc[4][2];
#pragma unroll
    for (int mi = 0; mi < 4; ++mi)
#pragma unroll
        for (int ni = 0; ni < 2; ++ni) acc[mi][ni] = {0.f, 0.f, 0.f, 0.f};

    // staging: thread t covers A row t>>2 (k (t&3)*8 .. +8, both 32-halves)
    // and B rows t>>2, 64+(t>>2).
    const int kb = (tid & 3) * 8;
    const int rT = tid >> 2;
    const unsigned short* Ag  = A + (size_t)(m0 + rT) * K + kb;
    const unsigned short* Bg0 = Bt + (size_t)(n0 + rT) * K + kb;
    const unsigned short* Bg1 = Bt + (size_t)(n0 + 64 + rT) * K + kb;
    const int aOff  = rT * LSTRIDE + kb;
    const int b0Off = rT * LSTRIDE + kb;
    const int b1Off = (64 + rT) * LSTRIDE + kb;

    const int NK = K >> 6;   // K/64
    bf16x8 R[2][6];
    // prologue: load tiles 0,1 into the two register sets
#pragma unroll
    for (int p = 0; p < 2; ++p) {
        const int ko = p * 64;
        R[p][0] = *(const bf16x8*)(Ag + ko);
        R[p][1] = *(const bf16x8*)(Ag + ko + 32);
        R[p][2] = *(const bf16x8*)(Bg0 + ko);
        R[p][3] = *(const bf16x8*)(Bg0 + ko + 32);
        R[p][4] = *(const bf16x8*)(Bg1 + ko);
        R[p][5] = *(const bf16x8*)(Bg1 + ko + 32);
    }
    // publish tile 0
    *(bf16x8*)(As[0] + aOff)       = R[0][0];
    *(bf16x8*)(As[0] + aOff + 32)  = R[0][1];
    *(bf16x8*)(Bs[0] + b0Off)      = R[0][2];
    *(bf16x8*)(Bs[0] + b0Off + 32) = R[0][3];
    *(bf16x8*)(Bs[0] + b1Off)      = R[0][4];
    *(bf16x8*)(Bs[0] + b1Off + 32) = R[0][5];
    lds_barrier();

    for (int i = 0; i < NK; ++i) {
        const int cur = i & 1, nxt = cur ^ 1;
        // 1. prefetch tile i+2 into the register set just freed (tile i's)
        if (i + 2 < NK) {
            const int ko = (i + 2) * 64;
            R[cur][0] = *(const bf16x8*)(Ag + ko);
            R[cur][1] = *(const bf16x8*)(Ag + ko + 32);
            R[cur][2] = *(const bf16x8*)(Bg0 + ko);
            R[cur][3] = *(const bf16x8*)(Bg0 + ko + 32);
            R[cur][4] = *(const bf16x8*)(Bg1 + ko);
            R[cur][5] = *(const bf16x8*)(Bg1 + ko + 32);
        }
        // 2. compute tile i from buf[cur]
#pragma unroll
        for (int ks = 0; ks < 2; ++ks) {
            bf16x8 af[4], bfr[2];
#pragma unroll
            for (int mi = 0; mi < 4; ++mi)
                af[mi] = *(const bf16x8*)(As[cur] + (mi * 16 + mr) * LSTRIDE +
                                          ks * 32 + q * 8);
#pragma unroll
            for (int ni = 0; ni < 2; ++ni)
                bfr[ni] = *(const bf16x8*)(Bs[cur] + (wave * 32 + ni * 16 + mr) * LSTRIDE +
                                           ks * 32 + q * 8);
#pragma unroll
            for (int mi = 0; mi < 4; ++mi)
#pragma unroll
                for (int ni = 0; ni < 2; ++ni)
                    acc[mi][ni] = __builtin_amdgcn_mfma_f32_16x16x32_bf16(
                        af[mi], bfr[ni], acc[mi][ni], 0, 0, 0);
        }
        // 3. publish tile i+1 (regs loaded 1-2 iters ago; fine-grained vmcnt here)
        if (i + 1 < NK) {
            *(bf16x8*)(As[nxt] + aOff)       = R[nxt][0];
            *(bf16x8*)(As[nxt] + aOff + 32)  = R[nxt][1];
            *(bf16x8*)(Bs[nxt] + b0Off)      = R[nxt][2];
            *(bf16x8*)(Bs[nxt] + b0Off + 32) = R[nxt][3];
            *(bf16x8*)(Bs[nxt] + b1Off)      = R[nxt][4];
            *(bf16x8*)(Bs[nxt] + b1Off + 32) = R[nxt][5];
            lds_barrier();   // lgkm-only: prefetch loads stay in flight
        }
    }

    // epilogue: C/D layout col = lane&15, row = q*4 + r
#pragma unroll
    for (int ni = 0; ni < 2; ++ni) {
        const int col = n0 + wave * 32 + ni * 16 + mr;
        float be = 0.f, al = 0.f;
        if (EPI == 3 && col < 1024) { be = bias[col]; al = alog[col]; }
#pragma unroll
        for (int mi = 0; mi < 4; ++mi) {
            const int row0 = m0 + mi * 16 + q * 4;
#pragma unroll
            for (int r = 0; r < 4; ++r) {
                float v = acc[mi][ni][r];
                const int row = row0 + r;
                if (EPI == 0) {
                    ((float*)Cout)[(size_t)row * N + col] = v;
                } else if (EPI == 2) {
                    ((unsigned short*)Cout)[(size_t)row * N + col] = f2bf(v);
                } else {  // EPI == 3
                    if (col < 1024) {
                        float dt = softplus_f(v + be);
                        ((unsigned short*)Cout)[(size_t)row * 1024 + col] =
                            f2bf(expf(dt * (-expf(al))));
                    } else if (col < 1056) {
                        bc[(size_t)row * 32 + (col - 1024)] = v;
                    }
                }
            }
        }
    }
}

// ---------------------------------------------------------------------------
// Depthwise causal conv (4 taps) + bias + SiLU, bf16 in/out. 8 channels/thread.
// ---------------------------------------------------------------------------
__global__ __launch_bounds__(256) void conv_silu_kernel(
        const unsigned short* __restrict__ xz, const float* __restrict__ conv_w,
        const float* __restrict__ conv_b, unsigned short* __restrict__ xssm) {
    const int idx = blockIdx.x * 256 + threadIdx.x;   // MROWS*128 threads
    const int d8 = idx & 127;
    const int bt = idx >> 7;
    const int t  = bt & (SEQ - 1);
    const int d  = d8 * 8;

    float4 w[8];
#pragma unroll
    for (int i = 0; i < 8; ++i) w[i] = *(const float4*)&conv_w[(d + i) * 4];

    float acc[8];
    {
        const float4 b0 = *(const float4*)&conv_b[d];
        const float4 b1 = *(const float4*)&conv_b[d + 4];
        acc[0] = b0.x; acc[1] = b0.y; acc[2] = b0.z; acc[3] = b0.w;
        acc[4] = b1.x; acc[5] = b1.y; acc[6] = b1.z; acc[7] = b1.w;
    }

#pragma unroll
    for (int j = 0; j < D_CONV; ++j) {
        const int tt = t - (D_CONV - 1) + j;
        if (tt < 0) continue;   // wave-uniform
        const bf16x8 xv = *(const bf16x8*)(&xz[((size_t)(bt - t + tt)) * 2048 + d]);
        const float wj[8] = {j == 0 ? w[0].x : j == 1 ? w[0].y : j == 2 ? w[0].z : w[0].w,
                             j == 0 ? w[1].x : j == 1 ? w[1].y : j == 2 ? w[1].z : w[1].w,
                             j == 0 ? w[2].x : j == 1 ? w[2].y : j == 2 ? w[2].z : w[2].w,
                             j == 0 ? w[3].x : j == 1 ? w[3].y : j == 2 ? w[3].z : w[3].w,
                             j == 0 ? w[4].x : j == 1 ? w[4].y : j == 2 ? w[4].z : w[4].w,
                             j == 0 ? w[5].x : j == 1 ? w[5].y : j == 2 ? w[5].z : w[5].w,
                             j == 0 ? w[6].x : j == 1 ? w[6].y : j == 2 ? w[6].z : w[6].w,
                             j == 0 ? w[7].x : j == 1 ? w[7].y : j == 2 ? w[7].z : w[7].w};
#pragma unroll
        for (int i = 0; i < 8; ++i)
            acc[i] += bf2f((unsigned short)xv[i]) * wj[i];
    }
    bf16x8 o;
#pragma unroll
    for (int i = 0; i < 8; ++i) {
        const float s = acc[i] / (1.f + expf(-acc[i]));
        o[i] = (short)f2bf(s);
    }
    *(bf16x8*)(&xssm[(size_t)bt * D_MODEL + d]) = o;
}

// ---------------------------------------------------------------------------
// Chunked selective scan, channel-per-lane (h[16] in regs), bf16 dA.
// ---------------------------------------------------------------------------
__global__ __launch_bounds__(256) void scan_pass1(
        const unsigned short* __restrict__ xssm, const unsigned short* __restrict__ dA16,
        const float* __restrict__ BCb,
        float* __restrict__ Sbuf, float* __restrict__ Pbuf) {
    const int ch = blockIdx.x, dg = blockIdx.y, b = blockIdx.z;
    const int tid = threadIdx.x;
    const int dd  = dg * 256 + tid;
    const int t0  = ch * CHUNK;

    __shared__ float Bs[CHUNK][16];
    if (tid < CHUNK * 4) {
        const int t = tid >> 2, j = (tid & 3) * 4;
        *(float4*)&Bs[t][j] = *(const float4*)&BCb[((size_t)b * SEQ + t0 + t) * 32 + j];
    }
    __syncthreads();

    const size_t base = ((size_t)b * SEQ + t0) * D_MODEL + dd;
    float h[16];
#pragma unroll
    for (int n = 0; n < 16; ++n) h[n] = 0.f;
    float P = 1.f;

    for (int g = 0; g < CHUNK; g += 8) {
        float dAr[8], xr[8];
#pragma unroll
        for (int p = 0; p < 8; ++p) {
            const size_t o = base + (size_t)(g + p) * D_MODEL;
            dAr[p] = bf2f(dA16[o]);
            xr[p]  = bf2f(xssm[o]);
        }
#pragma unroll
        for (int p = 0; p < 8; ++p) {
            const int t = g + p;
            const float dA = dAr[p], x = xr[p];
            P *= dA;
            const float4 B0 = *(const float4*)&Bs[t][0];
            const float4 B1 = *(const float4*)&Bs[t][4];
            const float4 B2 = *(const float4*)&Bs[t][8];
            const float4 B3 = *(const float4*)&Bs[t][12];
            h[0]  = h[0]  * dA + x * B0.x;  h[1]  = h[1]  * dA + x * B0.y;
            h[2]  = h[2]  * dA + x * B0.z;  h[3]  = h[3]  * dA + x * B0.w;
            h[4]  = h[4]  * dA + x * B1.x;  h[5]  = h[5]  * dA + x * B1.y;
            h[6]  = h[6]  * dA + x * B1.z;  h[7]  = h[7]  * dA + x * B1.w;
            h[8]  = h[8]  * dA + x * B2.x;  h[9]  = h[9]  * dA + x * B2.y;
            h[10] = h[10] * dA + x * B2.z;  h[11] = h[11] * dA + x * B2.w;
            h[12] = h[12] * dA + x * B3.x;  h[13] = h[13] * dA + x * B3.y;
            h[14] = h[14] * dA + x * B3.z;  h[15] = h[15] * dA + x * B3.w;
        }
    }

    const int dn = b * D_MODEL + dd;
    const size_t so = ((size_t)ch * BD + dn) * 16;
#pragma unroll
    for (int n = 0; n < 16; n += 4)
        *(float4*)&Sbuf[so + n] = make_float4(h[n], h[n + 1], h[n + 2], h[n + 3]);
    Pbuf[(size_t)ch * BD + dn] = P;
}

// Sequential combine over chunks. Thread per (b,d,n) = 32768 threads.
__global__ __launch_bounds__(128) void scan_mid(
        const float* __restrict__ Sbuf, const float* __restrict__ Pbuf,
        float* __restrict__ Hin) {
    const int idx = blockIdx.x * 128 + threadIdx.x;   // dn*16 + n
    const int n   = idx & 15;
    const int dn  = idx >> 4;

    float h = 0.f;
    for (int ch = 0; ch < NCHUNK; ++ch) {
        const size_t s = ((size_t)ch * BD + dn) * 16 + n;
        Hin[s] = h;
        h = Pbuf[(size_t)ch * BD + dn] * h + Sbuf[s];
    }
}

__global__ __launch_bounds__(256) void scan_pass2(
        const unsigned short* __restrict__ xssm, const unsigned short* __restrict__ dA16,
        const float* __restrict__ BCb, const unsigned short* __restrict__ xz,
        const float* __restrict__ Dp, const float* __restrict__ Hin,
        unsigned short* __restrict__ ybuf) {
    const int ch = blockIdx.x, dg = blockIdx.y, b = blockIdx.z;
    const int tid = threadIdx.x;
    const int dd  = dg * 256 + tid;
    const int t0  = ch * CHUNK;

    __shared__ float BCs[CHUNK][32];
    {
        const int t = tid >> 3, j = (tid & 7) * 4;
        *(float4*)&BCs[t][j] = *(const float4*)&BCb[((size_t)b * SEQ + t0 + t) * 32 + j];
    }
    __syncthreads();

    const float Dpv = Dp[dd];
    const size_t base  = ((size_t)b * SEQ + t0) * D_MODEL + dd;
    const size_t baseZ = ((size_t)b * SEQ + t0) * 2048 + D_MODEL + dd;

    float h[16];
    const int dn = b * D_MODEL + dd;
    const size_t ho = ((size_t)ch * BD + dn) * 16;
#pragma unroll
    for (int n = 0; n < 16; n += 4) {
        const float4 hv = *(const float4*)&Hin[ho + n];
        h[n] = hv.x; h[n + 1] = hv.y; h[n + 2] = hv.z; h[n + 3] = hv.w;
    }

    for (int g = 0; g < CHUNK; g += 8) {
        float dAr[8], xr[8], zr[8];
#pragma unroll
        for (int p = 0; p < 8; ++p) {
            const size_t o = base + (size_t)(g + p) * D_MODEL;
            dAr[p] = bf2f(dA16[o]);
            xr[p]  = bf2f(xssm[o]);
            zr[p]  = bf2f(xz[baseZ + (size_t)(g + p) * 2048]);
        }
#pragma unroll
        for (int p = 0; p < 8; ++p) {
            const int t = g + p;
            const float dA = dAr[p], x = xr[p];
            const float4 B0 = *(const float4*)&BCs[t][0];
            const float4 B1 = *(const float4*)&BCs[t][4];
            const float4 B2 = *(const float4*)&BCs[t][8];
            const float4 B3 = *(const float4*)&BCs[t][12];
            const float4 C0 = *(const float4*)&BCs[t][16];
            const float4 C1 = *(const float4*)&BCs[t][20];
            const float4 C2 = *(const float4*)&BCs[t][24];
            const float4 C3 = *(const float4*)&BCs[t][28];
            float y = 0.f;
            h[0]  = h[0]  * dA + x * B0.x;  y += h[0]  * C0.x;
            h[1]  = h[1]  * dA + x * B0.y;  y += h[1]  * C0.y;
            h[2]  = h[2]  * dA + x * B0.z;  y += h[2]  * C0.z;
            h[3]  = h[3]  * dA + x * B0.w;  y += h[3]  * C0.w;
            h[4]  = h[4]  * dA + x * B1.x;  y += h[4]  * C1.x;
            h[5]  = h[5]  * dA + x * B1.y;  y += h[5]  * C1.y;
            h[6]  = h[6]  * dA + x * B1.z;  y += h[6]  * C1.z;
            h[7]  = h[7]  * dA + x * B1.w;  y += h[7]  * C1.w;
            h[8]  = h[8]  * dA + x * B2.x;  y += h[8]  * C2.x;
            h[9]  = h[9]  * dA + x * B2.y;  y += h[9]  * C2.y;
            h[10] = h[10] * dA + x * B2.z;  y += h[10] * C2.z;
            h[11] = h[11] * dA + x * B2.w;  y += h[11] * C2.w;
            h[12] = h[12] * dA + x * B3.x;  y += h[12] * C3.x;
            h[13] = h[13] * dA + x * B3.y;  y += h[13] * C3.y;
            h[14] = h[14] * dA + x * B3.z;  y += h[14] * C3.z;
            h[15] = h[15] * dA + x * B3.w;  y += h[15] * C3.w;

            const float zv = zr[p];
            const float sz = zv / (1.f + expf(-zv));
            ybuf[base + (size_t)t * D_MODEL] = f2bf((y + x * Dpv) * sz);
        }
    }
}

// ---------------------------------------------------------------------------
extern "C" void kernel_launch(void* const* d_in, const int* in_sizes, int n_in,
                              void* d_out, int out_size, void* d_ws, size_t ws_size,
                              hipStream_t stream) {
    const float* x       = (const float*)d_in[0];
    const float* W_in    = (const float*)d_in[1];
    const float* conv_w  = (const float*)d_in[2];
    const float* conv_b  = (const float*)d_in[3];
    const float* W_x     = (const float*)d_in[4];
    const float* W_dt    = (const float*)d_in[5];
    const float* b_dt    = (const float*)d_in[6];
    const float* A_log   = (const float*)d_in[7];
    const float* D_param = (const float*)d_in[8];
    const float* W_out   = (const float*)d_in[9];
    float* out = (float*)d_out;
    char* ws   = (char*)d_ws;

    // byte-offset workspace layout; total ~85.2 MB
    unsigned short* xz_bf   = (unsigned short*)(ws + 0);           // 16,777,216 B
    unsigned short* xssm_bf = (unsigned short*)(ws + 16777216);    //  8,388,608
    unsigned short* dAb16   = (unsigned short*)(ws + 25165824);    //  8,388,608 (bf16)
    float*          BCb     = (float*)(ws + 41943040);             //    524,288
    unsigned short* ybuf_bf = (unsigned short*)(ws + 42467328);    //  8,388,608
    unsigned short* xb      = (unsigned short*)(ws + 50855936);    //  8,388,608
    unsigned short* Wt_in   = (unsigned short*)(ws + 59244544);    //  4,194,304
    unsigned short* Wt_cat  = (unsigned short*)(ws + 63438848);    //  2,359,296 (1152x1024)
    unsigned short* Wt_out  = (unsigned short*)(ws + 65798144);    //  2,097,152
    float*          Sbuf    = (float*)(ws + 67895296);             //  8,388,608
    float*          Pbuf    = (float*)(ws + 76283904);             //    524,288
    float*          Hin     = (float*)(ws + 76808192);             //  8,388,608 -> 85,196,800

    // 0. merged prepass: cvt x + 3 transposes + wx stage (6656 blocks)
    prepass<<<2048 + 2048 + 1024 + 1024 + 512, 256, 0, stream>>>(
        x, xb, W_in, Wt_in, W_dt, Wt_cat, W_out, Wt_out, W_x);

    // 1. xz = x @ W_in  (bf16 out)  — 1024 blocks
    gemm64<2><<<dim3(2048 / 128, MROWS / 64), 256, 0, stream>>>(
        xb, Wt_in, xz_bf, 2048, D_MODEL, nullptr, nullptr, nullptr);
    // 2. depthwise conv + silu (8 ch/thread)
    conv_silu_kernel<<<(MROWS * 128) / 256, 256, 0, stream>>>(xz_bf, conv_w, conv_b, xssm_bf);
    // 3. fused: dA (bf16) = exp(softplus(xssm@W_dt + b_dt) * -exp(A_log)) AND BC = xssm@W_x
    gemm64<3><<<dim3(1152 / 128, MROWS / 64), 256, 0, stream>>>(
        xssm_bf, Wt_cat, dAb16, 1152, D_MODEL, b_dt, A_log, BCb);
    // 4. chunked selective scan + D-skip + z-gate
    scan_pass1<<<dim3(NCHUNK, D_MODEL / 256, BATCH), 256, 0, stream>>>(
        xssm_bf, dAb16, BCb, Sbuf, Pbuf);
    scan_mid<<<(BD * 16) / 128, 128, 0, stream>>>(Sbuf, Pbuf, Hin);
    scan_pass2<<<dim3(NCHUNK, D_MODEL / 256, BATCH), 256, 0, stream>>>(
        xssm_bf, dAb16, BCb, xz_bf, D_param, Hin, ybuf_bf);
    // 5. out = y @ W_out  (fp32 out)
    gemm64<0><<<dim3(1024 / 128, MROWS / 64), 256, 0, stream>>>(
        ybuf_bf, Wt_out, out, D_MODEL, D_MODEL, nullptr, nullptr, nullptr);
}

// Round 10
// 253.698 us; speedup vs baseline: 1.6677x; 1.6677x over previous
//
#include <hip/hip_runtime.h>
#include <hip/hip_bf16.h>
#include <math.h>

#define D_MODEL 1024
#define D_STATE 16
#define D_CONV  4
#define BATCH   2
#define SEQ     2048
#define MROWS   (BATCH * SEQ)   // 4096
#define CHUNK   32
#define NCHUNK  (SEQ / CHUNK)   // 64
#define BD      (BATCH * D_MODEL)   // 2048

typedef __attribute__((ext_vector_type(8))) short bf16x8;
typedef __attribute__((ext_vector_type(4))) float f32x4;

#define LSTRIDE 68   // LDS row stride in elems (136 B): staggers ds_read banks

__device__ __forceinline__ unsigned short f2bf(float f) {
    unsigned int u = __builtin_bit_cast(unsigned int, f);
    u = (u + 0x7fffu + ((u >> 16) & 1u)) >> 16;
    return (unsigned short)u;
}
__device__ __forceinline__ float bf2f(unsigned short u) {
    return __builtin_bit_cast(float, (unsigned int)u << 16);
}
__device__ __forceinline__ float softplus_f(float v) {
    return (v > 20.f) ? v : log1pf(expf(v));
}

// barrier that does NOT drain vmcnt: publish LDS ops (lgkmcnt(0)) + s_barrier.
// 0xc07f = vmcnt(63) expcnt(7) lgkmcnt(0)
__device__ __forceinline__ void lds_barrier() {
    __builtin_amdgcn_s_waitcnt(0xc07f);
    __builtin_amdgcn_s_barrier();
}

// ---------------------------------------------------------------------------
// Merged prepass (unchanged)
// ---------------------------------------------------------------------------
__global__ __launch_bounds__(256) void prepass(
        const float* __restrict__ x, unsigned short* __restrict__ xb,
        const float* __restrict__ W_in, unsigned short* __restrict__ Wt_in,
        const float* __restrict__ W_dt, unsigned short* __restrict__ Wt_cat,
        const float* __restrict__ W_out, unsigned short* __restrict__ Wt_out,
        const float* __restrict__ Wx) {
    __shared__ float tile[32][33];
    const int blk = blockIdx.x;
    const int tid = threadIdx.x;

    if (blk < 2048) {                       // region 0: cvt x
        const size_t i = ((size_t)blk * 256 + tid) * 8;
        const float4 v0 = *(const float4*)(x + i);
        const float4 v1 = *(const float4*)(x + i + 4);
        bf16x8 o;
        o[0] = (short)f2bf(v0.x); o[1] = (short)f2bf(v0.y);
        o[2] = (short)f2bf(v0.z); o[3] = (short)f2bf(v0.w);
        o[4] = (short)f2bf(v1.x); o[5] = (short)f2bf(v1.y);
        o[6] = (short)f2bf(v1.z); o[7] = (short)f2bf(v1.w);
        *(bf16x8*)(xb + i) = o;
        return;
    }
    if (blk < 2048 + 2048 + 1024 + 1024) {  // regions 1-3: transpose
        const float* W; unsigned short* Wt; int N, b;
        if (blk < 4096)      { W = W_in;  Wt = Wt_in;  N = 2048; b = blk - 2048; }
        else if (blk < 5120) { W = W_dt;  Wt = Wt_cat; N = 1024; b = blk - 4096; }
        else                 { W = W_out; Wt = Wt_out; N = 1024; b = blk - 5120; }
        const int nx = N / 32;
        const int n0 = (b % nx) * 32, k0 = (b / nx) * 32;
        const int tx = tid & 31, ty = tid >> 5;
#pragma unroll
        for (int r = 0; r < 4; ++r)
            tile[ty + r * 8][tx] = W[(size_t)(k0 + ty + r * 8) * N + n0 + tx];
        __syncthreads();
#pragma unroll
        for (int r = 0; r < 4; ++r)
            Wt[(size_t)(n0 + ty + r * 8) * 1024 + k0 + tx] = f2bf(tile[tx][ty + r * 8]);
        return;
    }
    {                                        // region 4: wx_stage
        const int idx = (blk - 6144) * 256 + tid;
        const int k = idx & 1023;
        const int n = idx >> 10;
        unsigned short v = 0;
        if (n < 32) v = f2bf(Wx[(size_t)k * 32 + n]);
        Wt_cat[(size_t)(1024 + n) * 1024 + k] = v;
    }
}

// ---------------------------------------------------------------------------
// MFMA GEMM, register-staged pipeline with STATIC unroll-by-2 (no dynamic
// private-array indexing -> no scratch). 64x128 tile, BK=64, NK = K/64 even.
//   even i: prefetch tile i+2 -> R0; compute buf0; publish R1 -> buf1; barrier
//   odd  i: prefetch tile i+3 -> R1; compute buf1; publish R0 -> buf0; barrier
// Barriers are lgkm-only: global loads stay in flight across them.
// ---------------------------------------------------------------------------
#define LOAD_SET(R, ko)                                   \
    do {                                                  \
        R##a = *(const bf16x8*)(Ag + (ko));               \
        R##b = *(const bf16x8*)(Ag + (ko) + 32);          \
        R##c = *(const bf16x8*)(Bg0 + (ko));              \
        R##d = *(const bf16x8*)(Bg0 + (ko) + 32);         \
        R##e = *(const bf16x8*)(Bg1 + (ko));              \
        R##f = *(const bf16x8*)(Bg1 + (ko) + 32);         \
    } while (0)

#define PUBLISH_SET(R, buf)                               \
    do {                                                  \
        *(bf16x8*)(As[buf] + aOff)       = R##a;          \
        *(bf16x8*)(As[buf] + aOff + 32)  = R##b;          \
        *(bf16x8*)(Bs[buf] + b0Off)      = R##c;          \
        *(bf16x8*)(Bs[buf] + b0Off + 32) = R##d;          \
        *(bf16x8*)(Bs[buf] + b1Off)      = R##e;          \
        *(bf16x8*)(Bs[buf] + b1Off + 32) = R##f;          \
    } while (0)

#define COMPUTE_TILE(buf)                                                        \
    do {                                                                         \
        _Pragma("unroll")                                                        \
        for (int ks = 0; ks < 2; ++ks) {                                         \
            bf16x8 af[4], bfr[2];                                                \
            _Pragma("unroll")                                                    \
            for (int mi = 0; mi < 4; ++mi)                                       \
                af[mi] = *(const bf16x8*)(As[buf] + (mi * 16 + mr) * LSTRIDE +   \
                                          ks * 32 + q * 8);                      \
            _Pragma("unroll")                                                    \
            for (int ni = 0; ni < 2; ++ni)                                       \
                bfr[ni] = *(const bf16x8*)(Bs[buf] +                             \
                                           (wave * 32 + ni * 16 + mr) * LSTRIDE +\
                                           ks * 32 + q * 8);                     \
            _Pragma("unroll")                                                    \
            for (int mi = 0; mi < 4; ++mi)                                       \
                _Pragma("unroll")                                                \
                for (int ni = 0; ni < 2; ++ni)                                   \
                    acc[mi][ni] = __builtin_amdgcn_mfma_f32_16x16x32_bf16(       \
                        af[mi], bfr[ni], acc[mi][ni], 0, 0, 0);                  \
        }                                                                        \
    } while (0)

template <int EPI>
__global__ __launch_bounds__(256) void gemm64(
        const unsigned short* __restrict__ A, const unsigned short* __restrict__ Bt,
        void* __restrict__ Cout, int N, int K,
        const float* __restrict__ bias, const float* __restrict__ alog,
        float* __restrict__ bc) {
    __shared__ unsigned short As[2][64 * LSTRIDE];
    __shared__ unsigned short Bs[2][128 * LSTRIDE];

    const int tid  = threadIdx.x;
    const int wave = tid >> 6, lane = tid & 63;
    const int q = lane >> 4, mr = lane & 15;
    const int m0 = blockIdx.y * 64, n0 = blockIdx.x * 128;

    f32x4 acc[4][2];
#pragma unroll
    for (int mi = 0; mi < 4; ++mi)
#pragma unroll
        for (int ni = 0; ni < 2; ++ni) acc[mi][ni] = {0.f, 0.f, 0.f, 0.f};

    const int kb = (tid & 3) * 8;
    const int rT = tid >> 2;
    const unsigned short* Ag  = A + (size_t)(m0 + rT) * K + kb;
    const unsigned short* Bg0 = Bt + (size_t)(n0 + rT) * K + kb;
    const unsigned short* Bg1 = Bt + (size_t)(n0 + 64 + rT) * K + kb;
    const int aOff  = rT * LSTRIDE + kb;
    const int b0Off = rT * LSTRIDE + kb;
    const int b1Off = (64 + rT) * LSTRIDE + kb;

    const int NK = K >> 6;   // always 16 here (even)
    bf16x8 R0a, R0b, R0c, R0d, R0e, R0f;
    bf16x8 R1a, R1b, R1c, R1d, R1e, R1f;

    // prologue: tile0 -> R0, tile1 -> R1, publish tile0, barrier
    LOAD_SET(R0, 0);
    LOAD_SET(R1, 64);
    PUBLISH_SET(R0, 0);
    lds_barrier();

    for (int i = 0; i < NK; i += 2) {
        // ---- even: compute tile i from buf0 ----
        if (i + 2 < NK) LOAD_SET(R0, (i + 2) * 64);
        COMPUTE_TILE(0);
        if (i + 1 < NK) {
            PUBLISH_SET(R1, 1);
            lds_barrier();
        }
        // ---- odd: compute tile i+1 from buf1 ----
        if (i + 3 < NK) LOAD_SET(R1, (i + 3) * 64);
        if (i + 1 < NK) COMPUTE_TILE(1);
        if (i + 2 < NK) {
            PUBLISH_SET(R0, 0);
            lds_barrier();
        }
    }

    // epilogue: C/D layout col = lane&15, row = q*4 + r
#pragma unroll
    for (int ni = 0; ni < 2; ++ni) {
        const int col = n0 + wave * 32 + ni * 16 + mr;
        float be = 0.f, al = 0.f;
        if (EPI == 3 && col < 1024) { be = bias[col]; al = alog[col]; }
#pragma unroll
        for (int mi = 0; mi < 4; ++mi) {
            const int row0 = m0 + mi * 16 + q * 4;
#pragma unroll
            for (int r = 0; r < 4; ++r) {
                float v = acc[mi][ni][r];
                const int row = row0 + r;
                if (EPI == 0) {
                    ((float*)Cout)[(size_t)row * N + col] = v;
                } else if (EPI == 2) {
                    ((unsigned short*)Cout)[(size_t)row * N + col] = f2bf(v);
                } else {  // EPI == 3
                    if (col < 1024) {
                        float dt = softplus_f(v + be);
                        ((unsigned short*)Cout)[(size_t)row * 1024 + col] =
                            f2bf(expf(dt * (-expf(al))));
                    } else if (col < 1056) {
                        bc[(size_t)row * 32 + (col - 1024)] = v;
                    }
                }
            }
        }
    }
}

// ---------------------------------------------------------------------------
// Depthwise causal conv (4 taps) + bias + SiLU, bf16 in/out. 8 channels/thread.
// ---------------------------------------------------------------------------
__global__ __launch_bounds__(256) void conv_silu_kernel(
        const unsigned short* __restrict__ xz, const float* __restrict__ conv_w,
        const float* __restrict__ conv_b, unsigned short* __restrict__ xssm) {
    const int idx = blockIdx.x * 256 + threadIdx.x;
    const int d8 = idx & 127;
    const int bt = idx >> 7;
    const int t  = bt & (SEQ - 1);
    const int d  = d8 * 8;

    float4 w[8];
#pragma unroll
    for (int i = 0; i < 8; ++i) w[i] = *(const float4*)&conv_w[(d + i) * 4];

    float acc[8];
    {
        const float4 b0 = *(const float4*)&conv_b[d];
        const float4 b1 = *(const float4*)&conv_b[d + 4];
        acc[0] = b0.x; acc[1] = b0.y; acc[2] = b0.z; acc[3] = b0.w;
        acc[4] = b1.x; acc[5] = b1.y; acc[6] = b1.z; acc[7] = b1.w;
    }

#pragma unroll
    for (int j = 0; j < D_CONV; ++j) {
        const int tt = t - (D_CONV - 1) + j;
        if (tt < 0) continue;
        const bf16x8 xv = *(const bf16x8*)(&xz[((size_t)(bt - t + tt)) * 2048 + d]);
        const float wj[8] = {j == 0 ? w[0].x : j == 1 ? w[0].y : j == 2 ? w[0].z : w[0].w,
                             j == 0 ? w[1].x : j == 1 ? w[1].y : j == 2 ? w[1].z : w[1].w,
                             j == 0 ? w[2].x : j == 1 ? w[2].y : j == 2 ? w[2].z : w[2].w,
                             j == 0 ? w[3].x : j == 1 ? w[3].y : j == 2 ? w[3].z : w[3].w,
                             j == 0 ? w[4].x : j == 1 ? w[4].y : j == 2 ? w[4].z : w[4].w,
                             j == 0 ? w[5].x : j == 1 ? w[5].y : j == 2 ? w[5].z : w[5].w,
                             j == 0 ? w[6].x : j == 1 ? w[6].y : j == 2 ? w[6].z : w[6].w,
                             j == 0 ? w[7].x : j == 1 ? w[7].y : j == 2 ? w[7].z : w[7].w};
#pragma unroll
        for (int i = 0; i < 8; ++i)
            acc[i] += bf2f((unsigned short)xv[i]) * wj[i];
    }
    bf16x8 o;
#pragma unroll
    for (int i = 0; i < 8; ++i) {
        const float s = acc[i] / (1.f + expf(-acc[i]));
        o[i] = (short)f2bf(s);
    }
    *(bf16x8*)(&xssm[(size_t)bt * D_MODEL + d]) = o;
}

// ---------------------------------------------------------------------------
// Chunked selective scan (unchanged from R8)
// ---------------------------------------------------------------------------
__global__ __launch_bounds__(256) void scan_pass1(
        const unsigned short* __restrict__ xssm, const unsigned short* __restrict__ dA16,
        const float* __restrict__ BCb,
        float* __restrict__ Sbuf, float* __restrict__ Pbuf) {
    const int ch = blockIdx.x, dg = blockIdx.y, b = blockIdx.z;
    const int tid = threadIdx.x;
    const int dd  = dg * 256 + tid;
    const int t0  = ch * CHUNK;

    __shared__ float Bs[CHUNK][16];
    if (tid < CHUNK * 4) {
        const int t = tid >> 2, j = (tid & 3) * 4;
        *(float4*)&Bs[t][j] = *(const float4*)&BCb[((size_t)b * SEQ + t0 + t) * 32 + j];
    }
    __syncthreads();

    const size_t base = ((size_t)b * SEQ + t0) * D_MODEL + dd;
    float h[16];
#pragma unroll
    for (int n = 0; n < 16; ++n) h[n] = 0.f;
    float P = 1.f;

    for (int g = 0; g < CHUNK; g += 8) {
        float dAr[8], xr[8];
#pragma unroll
        for (int p = 0; p < 8; ++p) {
            const size_t o = base + (size_t)(g + p) * D_MODEL;
            dAr[p] = bf2f(dA16[o]);
            xr[p]  = bf2f(xssm[o]);
        }
#pragma unroll
        for (int p = 0; p < 8; ++p) {
            const int t = g + p;
            const float dA = dAr[p], x = xr[p];
            P *= dA;
            const float4 B0 = *(const float4*)&Bs[t][0];
            const float4 B1 = *(const float4*)&Bs[t][4];
            const float4 B2 = *(const float4*)&Bs[t][8];
            const float4 B3 = *(const float4*)&Bs[t][12];
            h[0]  = h[0]  * dA + x * B0.x;  h[1]  = h[1]  * dA + x * B0.y;
            h[2]  = h[2]  * dA + x * B0.z;  h[3]  = h[3]  * dA + x * B0.w;
            h[4]  = h[4]  * dA + x * B1.x;  h[5]  = h[5]  * dA + x * B1.y;
            h[6]  = h[6]  * dA + x * B1.z;  h[7]  = h[7]  * dA + x * B1.w;
            h[8]  = h[8]  * dA + x * B2.x;  h[9]  = h[9]  * dA + x * B2.y;
            h[10] = h[10] * dA + x * B2.z;  h[11] = h[11] * dA + x * B2.w;
            h[12] = h[12] * dA + x * B3.x;  h[13] = h[13] * dA + x * B3.y;
            h[14] = h[14] * dA + x * B3.z;  h[15] = h[15] * dA + x * B3.w;
        }
    }

    const int dn = b * D_MODEL + dd;
    const size_t so = ((size_t)ch * BD + dn) * 16;
#pragma unroll
    for (int n = 0; n < 16; n += 4)
        *(float4*)&Sbuf[so + n] = make_float4(h[n], h[n + 1], h[n + 2], h[n + 3]);
    Pbuf[(size_t)ch * BD + dn] = P;
}

__global__ __launch_bounds__(128) void scan_mid(
        const float* __restrict__ Sbuf, const float* __restrict__ Pbuf,
        float* __restrict__ Hin) {
    const int idx = blockIdx.x * 128 + threadIdx.x;
    const int n   = idx & 15;
    const int dn  = idx >> 4;

    float h = 0.f;
    for (int ch = 0; ch < NCHUNK; ++ch) {
        const size_t s = ((size_t)ch * BD + dn) * 16 + n;
        Hin[s] = h;
        h = Pbuf[(size_t)ch * BD + dn] * h + Sbuf[s];
    }
}

__global__ __launch_bounds__(256) void scan_pass2(
        const unsigned short* __restrict__ xssm, const unsigned short* __restrict__ dA16,
        const float* __restrict__ BCb, const unsigned short* __restrict__ xz,
        const float* __restrict__ Dp, const float* __restrict__ Hin,
        unsigned short* __restrict__ ybuf) {
    const int ch = blockIdx.x, dg = blockIdx.y, b = blockIdx.z;
    const int tid = threadIdx.x;
    const int dd  = dg * 256 + tid;
    const int t0  = ch * CHUNK;

    __shared__ float BCs[CHUNK][32];
    {
        const int t = tid >> 3, j = (tid & 7) * 4;
        *(float4*)&BCs[t][j] = *(const float4*)&BCb[((size_t)b * SEQ + t0 + t) * 32 + j];
    }
    __syncthreads();

    const float Dpv = Dp[dd];
    const size_t base  = ((size_t)b * SEQ + t0) * D_MODEL + dd;
    const size_t baseZ = ((size_t)b * SEQ + t0) * 2048 + D_MODEL + dd;

    float h[16];
    const int dn = b * D_MODEL + dd;
    const size_t ho = ((size_t)ch * BD + dn) * 16;
#pragma unroll
    for (int n = 0; n < 16; n += 4) {
        const float4 hv = *(const float4*)&Hin[ho + n];
        h[n] = hv.x; h[n + 1] = hv.y; h[n + 2] = hv.z; h[n + 3] = hv.w;
    }

    for (int g = 0; g < CHUNK; g += 8) {
        float dAr[8], xr[8], zr[8];
#pragma unroll
        for (int p = 0; p < 8; ++p) {
            const size_t o = base + (size_t)(g + p) * D_MODEL;
            dAr[p] = bf2f(dA16[o]);
            xr[p]  = bf2f(xssm[o]);
            zr[p]  = bf2f(xz[baseZ + (size_t)(g + p) * 2048]);
        }
#pragma unroll
        for (int p = 0; p < 8; ++p) {
            const int t = g + p;
            const float dA = dAr[p], x = xr[p];
            const float4 B0 = *(const float4*)&BCs[t][0];
            const float4 B1 = *(const float4*)&BCs[t][4];
            const float4 B2 = *(const float4*)&BCs[t][8];
            const float4 B3 = *(const float4*)&BCs[t][12];
            const float4 C0 = *(const float4*)&BCs[t][16];
            const float4 C1 = *(const float4*)&BCs[t][20];
            const float4 C2 = *(const float4*)&BCs[t][24];
            const float4 C3 = *(const float4*)&BCs[t][28];
            float y = 0.f;
            h[0]  = h[0]  * dA + x * B0.x;  y += h[0]  * C0.x;
            h[1]  = h[1]  * dA + x * B0.y;  y += h[1]  * C0.y;
            h[2]  = h[2]  * dA + x * B0.z;  y += h[2]  * C0.z;
            h[3]  = h[3]  * dA + x * B0.w;  y += h[3]  * C0.w;
            h[4]  = h[4]  * dA + x * B1.x;  y += h[4]  * C1.x;
            h[5]  = h[5]  * dA + x * B1.y;  y += h[5]  * C1.y;
            h[6]  = h[6]  * dA + x * B1.z;  y += h[6]  * C1.z;
            h[7]  = h[7]  * dA + x * B1.w;  y += h[7]  * C1.w;
            h[8]  = h[8]  * dA + x * B2.x;  y += h[8]  * C2.x;
            h[9]  = h[9]  * dA + x * B2.y;  y += h[9]  * C2.y;
            h[10] = h[10] * dA + x * B2.z;  y += h[10] * C2.z;
            h[11] = h[11] * dA + x * B2.w;  y += h[11] * C2.w;
            h[12] = h[12] * dA + x * B3.x;  y += h[12] * C3.x;
            h[13] = h[13] * dA + x * B3.y;  y += h[13] * C3.y;
            h[14] = h[14] * dA + x * B3.z;  y += h[14] * C3.z;
            h[15] = h[15] * dA + x * B3.w;  y += h[15] * C3.w;

            const float zv = zr[p];
            const float sz = zv / (1.f + expf(-zv));
            ybuf[base + (size_t)t * D_MODEL] = f2bf((y + x * Dpv) * sz);
        }
    }
}

// ---------------------------------------------------------------------------
extern "C" void kernel_launch(void* const* d_in, const int* in_sizes, int n_in,
                              void* d_out, int out_size, void* d_ws, size_t ws_size,
                              hipStream_t stream) {
    const float* x       = (const float*)d_in[0];
    const float* W_in    = (const float*)d_in[1];
    const float* conv_w  = (const float*)d_in[2];
    const float* conv_b  = (const float*)d_in[3];
    const float* W_x     = (const float*)d_in[4];
    const float* W_dt    = (const float*)d_in[5];
    const float* b_dt    = (const float*)d_in[6];
    const float* A_log   = (const float*)d_in[7];
    const float* D_param = (const float*)d_in[8];
    const float* W_out   = (const float*)d_in[9];
    float* out = (float*)d_out;
    char* ws   = (char*)d_ws;

    unsigned short* xz_bf   = (unsigned short*)(ws + 0);
    unsigned short* xssm_bf = (unsigned short*)(ws + 16777216);
    unsigned short* dAb16   = (unsigned short*)(ws + 25165824);
    float*          BCb     = (float*)(ws + 41943040);
    unsigned short* ybuf_bf = (unsigned short*)(ws + 42467328);
    unsigned short* xb      = (unsigned short*)(ws + 50855936);
    unsigned short* Wt_in   = (unsigned short*)(ws + 59244544);
    unsigned short* Wt_cat  = (unsigned short*)(ws + 63438848);
    unsigned short* Wt_out  = (unsigned short*)(ws + 65798144);
    float*          Sbuf    = (float*)(ws + 67895296);
    float*          Pbuf    = (float*)(ws + 76283904);
    float*          Hin     = (float*)(ws + 76808192);

    // 0. merged prepass
    prepass<<<2048 + 2048 + 1024 + 1024 + 512, 256, 0, stream>>>(
        x, xb, W_in, Wt_in, W_dt, Wt_cat, W_out, Wt_out, W_x);

    // 1. xz = x @ W_in  (bf16 out)
    gemm64<2><<<dim3(2048 / 128, MROWS / 64), 256, 0, stream>>>(
        xb, Wt_in, xz_bf, 2048, D_MODEL, nullptr, nullptr, nullptr);
    // 2. depthwise conv + silu
    conv_silu_kernel<<<(MROWS * 128) / 256, 256, 0, stream>>>(xz_bf, conv_w, conv_b, xssm_bf);
    // 3. fused dt/BC GEMM
    gemm64<3><<<dim3(1152 / 128, MROWS / 64), 256, 0, stream>>>(
        xssm_bf, Wt_cat, dAb16, 1152, D_MODEL, b_dt, A_log, BCb);
    // 4. chunked selective scan
    scan_pass1<<<dim3(NCHUNK, D_MODEL / 256, BATCH), 256, 0, stream>>>(
        xssm_bf, dAb16, BCb, Sbuf, Pbuf);
    scan_mid<<<(BD * 16) / 128, 128, 0, stream>>>(Sbuf, Pbuf, Hin);
    scan_pass2<<<dim3(NCHUNK, D_MODEL / 256, BATCH), 256, 0, stream>>>(
        xssm_bf, dAb16, BCb, xz_bf, D_param, Hin, ybuf_bf);
    // 5. out = y @ W_out
    gemm64<0><<<dim3(1024 / 128, MROWS / 64), 256, 0, stream>>>(
        ybuf_bf, Wt_out, out, D_MODEL, D_MODEL, nullptr, nullptr, nullptr);
}